// Round 1
// baseline (109.152 us; speedup 1.0000x reference)
//
#include <hip/hip_runtime.h>

// WindowEmbedding: x[B,T,D] fp32 -> out[B,T,D*W], slot w = x shifted left by w,
// zero-padded past end of sequence. B=16, T=2048, D=512, W=5.

constexpr int T_DIM = 2048;
constexpr int D4 = 128;   // 512 floats / 4 per float4
constexpr int W = 5;

__global__ __launch_bounds__(128) void window_embed_kernel(
    const float4* __restrict__ x, float4* __restrict__ out) {
    // One block per (b, t) output row. row = b*T + t.
    const int row = blockIdx.x;
    const int t = row & (T_DIM - 1);          // T is a power of 2
    const int tid = threadIdx.x;              // 0..127 -> float4 index within D

    // Output row base in float4 units: row * (W*D4) = row * 640
    long long out_base = (long long)row * (W * D4) + tid;

    const float4 zero = make_float4(0.f, 0.f, 0.f, 0.f);

#pragma unroll
    for (int w = 0; w < W; ++w) {
        float4 v = zero;
        if (t + w < T_DIM) {
            // source row = b*T + (t+w) = row + w (guard keeps it in-batch)
            v = x[(long long)(row + w) * D4 + tid];
        }
        out[out_base + (long long)w * D4] = v;
    }
}

extern "C" void kernel_launch(void* const* d_in, const int* in_sizes, int n_in,
                              void* d_out, int out_size, void* d_ws, size_t ws_size,
                              hipStream_t stream) {
    const float4* x = (const float4*)d_in[0];
    float4* out = (float4*)d_out;

    const int B = 16;
    const int grid = B * T_DIM;  // 32768 blocks, one per output row
    window_embed_kernel<<<grid, 128, 0, stream>>>(x, out);
}

// Round 2
// 72.883 us; speedup vs baseline: 1.4976x; 1.4976x over previous
//
#include <hip/hip_runtime.h>

// WindowEmbedding: x[B,T,D] fp32 -> out[B,T,D*W], slot w = x shifted left by w,
// zero past sequence end. B=16, T=2048, D=512, W=5.
//
// Identity used: out[(b*T+t)*640 + j] = x[(b*T+t)*128 + j] for j in [0,640),
// valid while t + j/128 < T (else 0). I.e. each output row is a contiguous
// 640-float4 slice of x. Blocks stage R+W-1 consecutive x rows in LDS once
// and emit R output rows -> global read amplification (R+4)/R instead of 5x.

typedef float f4 __attribute__((ext_vector_type(4)));

constexpr int T_DIM = 2048;
constexpr int D4 = 128;            // 512 floats / 4 per float4
constexpr int W = 5;
constexpr int R = 16;              // output rows per block
constexpr int SROWS = R + W - 1;   // 20 staged rows
constexpr int ROW_OUT = W * D4;    // 640 f4 per output row

__global__ __launch_bounds__(256) void window_embed_kernel(
    const f4* __restrict__ x, f4* __restrict__ out) {
  __shared__ f4 lds[SROWS * D4];   // 20 * 128 * 16B = 40 KiB

  const int tchunk = blockIdx.x;   // 0 .. T/R-1
  const int b = blockIdx.y;        // 0 .. B-1
  const int t0 = tchunk * R;
  const int tid = threadIdx.x;

  // ---- stage 20 rows (zero past end of sequence) ----
  const long long in_base = ((long long)b * T_DIM + t0) * D4;
#pragma unroll
  for (int k = 0; k < SROWS * D4 / 256; ++k) {   // 10 iters
    int f = k * 256 + tid;
    int r = f >> 7;                               // f / 128
    f4 v = (f4)0.f;
    if (t0 + r < T_DIM) v = x[in_base + f];
    lds[f] = v;
  }
  __syncthreads();

  // ---- emit R contiguous output rows from LDS ----
  // Process 2 output rows (1280 f4) per outer iter as 5 chunks of 256.
  const long long out_base = ((long long)b * T_DIM + t0) * ROW_OUT;
#pragma unroll 2
  for (int ii = 0; ii < R; ii += 2) {
#pragma unroll
    for (int q = 0; q < 5; ++q) {
      int o = q * 256 + tid;                 // 0..1279 within the 2-row span
      int hi = (o >= ROW_OUT) ? 1 : 0;       // second row of the pair?
      // lds index: (ii+hi)*128 + (o - 640*hi) = ii*128 + o - 512*hi
      f4 v = lds[ii * D4 + o - hi * 512];
      __builtin_nontemporal_store(
          v, &out[out_base + (long long)(ii + hi) * ROW_OUT + (o - hi * ROW_OUT)]);
    }
  }
}

extern "C" void kernel_launch(void* const* d_in, const int* in_sizes, int n_in,
                              void* d_out, int out_size, void* d_ws, size_t ws_size,
                              hipStream_t stream) {
  const f4* x = (const f4*)d_in[0];
  f4* out = (f4*)d_out;

  dim3 grid(T_DIM / R, 16);   // (128, 16) = 2048 blocks
  window_embed_kernel<<<grid, 256, 0, stream>>>(x, out);
}

// Round 3
// 70.224 us; speedup vs baseline: 1.5543x; 1.0379x over previous
//
#include <hip/hip_runtime.h>

// WindowEmbedding: x[B,T,D] fp32 -> out[B,T,D*W], slot w = x shifted left by w,
// zero past sequence end. B=16, T=2048, D=512, W=5.
//
// Identity: out[(b*T+t)*640 + j] = x[((b*T+t)*128) + j] for j in [0,640),
// valid while t + j/128 < T, else 0 -> each output row is a contiguous
// 640-float4 slice of x. Pure overlapping copy: each block owns R=32 rows,
// reads directly from global (re-reads of the 72 KiB window hit L1/L2 since
// the reuse is intra-block), nontemporal-stores the contiguous output.
// HBM read amplification = (R+W-1)/R = 1.125x.

typedef float f4 __attribute__((ext_vector_type(4)));

constexpr int T_DIM = 2048;
constexpr int D4 = 128;            // 512 floats / 4 per float4
constexpr int W = 5;
constexpr int R = 32;              // output rows per block
constexpr int ROW_OUT = W * D4;    // 640 f4 per output row

__global__ __launch_bounds__(256) void window_embed_kernel(
    const f4* __restrict__ x, f4* __restrict__ out) {
  const int tid  = threadIdx.x;
  const int lane = tid & 127;      // f4 index within a D-row
  const int half = tid >> 7;       // two 128-thread groups, 16 rows each

  const int t0 = blockIdx.x * R;
  const long long row0 = (long long)blockIdx.y * T_DIM + t0;

  const f4* __restrict__ xb = x + row0 * D4 + lane;
  f4* __restrict__ ob = out + row0 * (long long)ROW_OUT + lane;

  const f4 zero = (f4)0.f;

#pragma unroll 4
  for (int i = 0; i < R / 2; ++i) {
    const int r = half * (R / 2) + i;      // row within the block's chunk
    f4 v[W];
#pragma unroll
    for (int q = 0; q < W; ++q) {
      // source row t0 + r + q; guard past end of sequence
      v[q] = (t0 + r + q < T_DIM) ? xb[(r + q) * D4] : zero;
    }
#pragma unroll
    for (int q = 0; q < W; ++q) {
      __builtin_nontemporal_store(v[q], &ob[(long long)r * ROW_OUT + q * D4]);
    }
  }
}

extern "C" void kernel_launch(void* const* d_in, const int* in_sizes, int n_in,
                              void* d_out, int out_size, void* d_ws, size_t ws_size,
                              hipStream_t stream) {
  const f4* x = (const f4*)d_in[0];
  f4* out = (f4*)d_out;

  dim3 grid(T_DIM / R, 16);   // (64, 16) = 1024 blocks
  window_embed_kernel<<<grid, 256, 0, stream>>>(x, out);
}